// Round 1
// baseline (144839.819 us; speedup 1.0000x reference)
//
#include <hip/hip_runtime.h>
#include <cstdint>
#include <cstddef>

// MinGRU: B=16, S=2048, D=1024.
//   gates[b,t,:] = x[b,t,:] @ W_in + h[b,:] @ W_state + b_in     (2048 cols)
//   u = sigmoid(gates[:, :D]); c = tanh(gates[:, D:]); h' = h + u*(c-h)
// Persistent-kernel design: 256 blocks, grid barrier per timestep.
// Block j owns column-pairs p in [4j, 4j+4)  (update col p, candidate col D+p).
// Thread tau = b + 16*g;  g = cidx (0..7: 4 u-cols then 4 c-cols) | kh<<3 (K half).
// kh=0 half reads x_t and W_in columns; kh=1 half reads h_t and W_state columns.

#define BB 16
#define SS 2048
#define DD 1024
#define EE 2048          // 2*D
#define NB 256
#define NT 256
#define WSTRIDE 2064     // padded row stride (floats) for transposed W

__device__ __forceinline__ void grid_barrier(int* cnt, int* flg, int phase) {
  __syncthreads();
  if (threadIdx.x == 0) {
    __threadfence();  // publish our writes before arrival
    int t = __hip_atomic_fetch_add(cnt, 1, __ATOMIC_ACQ_REL, __HIP_MEMORY_SCOPE_AGENT);
    if (t == NB - 1) {
      __hip_atomic_store(cnt, 0, __ATOMIC_RELAXED, __HIP_MEMORY_SCOPE_AGENT);
      __hip_atomic_store(flg, phase, __ATOMIC_RELEASE, __HIP_MEMORY_SCOPE_AGENT);
    } else {
      while (__hip_atomic_load(flg, __ATOMIC_ACQUIRE, __HIP_MEMORY_SCOPE_AGENT) < phase) {
        __builtin_amdgcn_s_sleep(1);
      }
    }
    __threadfence();  // acquire: see everyone else's writes
  }
  __syncthreads();
}

__global__ __launch_bounds__(NT, 1) void mingru_persistent(
    const float* __restrict__ x, const float* __restrict__ h0,
    const float* __restrict__ W_in, const float* __restrict__ b_in,
    const float* __restrict__ W_state, float* __restrict__ out,
    float* __restrict__ wsf, int use_wt)
{
  int* cnt = (int*)wsf;
  int* flg = (int*)wsf + 1;
  float* hbuf = wsf + 64;             // 256 B in; hbuf[2][16][1024]
  float* WT   = hbuf + 2 * BB * DD;   // transposed W: WT[col][k], k<D from W_in, else W_state

  const int j   = blockIdx.x;
  const int tau = threadIdx.x;

  // ---- phase 0: h0 -> hbuf[0]; build WT (col-major-contiguous) ----
  for (int i = j * NT + tau; i < BB * DD; i += NB * NT) hbuf[i] = h0[i];
  if (use_wt) {
    for (int i = j * NT + tau; i < EE * EE; i += NB * NT) {
      int c = i >> 11;
      int k = i & 2047;
      float v = (k < DD) ? W_in[(size_t)k * EE + c]
                         : W_state[(size_t)(k - DD) * EE + c];
      WT[(size_t)c * WSTRIDE + k] = v;
    }
  }
  int phase = 1;
  grid_barrier(cnt, flg, phase++);

  // ---- role decode ----
  const int b    = tau & 15;
  const int g    = tau >> 4;          // 0..15
  const int cidx = g & 7;             // 0..7
  const int kh   = g >> 3;            // 0..1 (K half)
  const int p    = 4 * j + (cidx & 3);
  const int col  = (cidx < 4) ? p : (DD + p);

  __shared__ float red[NT];
  __shared__ float gat[128];

  const float* wcol_t = WT + (size_t)col * WSTRIDE + kh * DD;   // fast path
  const float* wsrc   = (kh == 0) ? W_in : W_state;             // fallback path
  const float  bias   = b_in[col];

  for (int t = 0; t < SS; ++t) {
    const float* hcur  = hbuf + (t & 1) * BB * DD;
    float*       hnext = hbuf + ((t + 1) & 1) * BB * DD;
    const float* xh = (kh == 0) ? (x + (size_t)b * SS * DD + (size_t)t * DD)
                                : (hcur + b * DD);
    float acc;
    if (use_wt) {
      const float4* xp = (const float4*)xh;
      const float4* wp = (const float4*)wcol_t;
      float4 a4 = make_float4(0.f, 0.f, 0.f, 0.f);
      #pragma unroll 8
      for (int i = 0; i < DD / 4; ++i) {
        float4 xv = xp[i];
        float4 wv = wp[i];
        a4.x += xv.x * wv.x; a4.y += xv.y * wv.y;
        a4.z += xv.z * wv.z; a4.w += xv.w * wv.w;
      }
      acc = (a4.x + a4.y) + (a4.z + a4.w);
    } else {
      float a0 = 0.f, a1 = 0.f, a2 = 0.f, a3 = 0.f;
      #pragma unroll 4
      for (int k = 0; k < DD; k += 4) {
        a0 += xh[k]     * wsrc[(size_t)k       * EE + col];
        a1 += xh[k + 1] * wsrc[(size_t)(k + 1) * EE + col];
        a2 += xh[k + 2] * wsrc[(size_t)(k + 2) * EE + col];
        a3 += xh[k + 3] * wsrc[(size_t)(k + 3) * EE + col];
      }
      acc = (a0 + a1) + (a2 + a3);
    }

    red[tau] = acc;
    __syncthreads();
    if (tau < 128) {                 // tau = b + 16*cidx here
      gat[tau] = red[tau] + red[tau + 128] + ((tau < 64) ? b_in[4 * j + (tau >> 4)]
                                                         : b_in[DD + 4 * j + ((tau >> 4) & 3)]);
    }
    __syncthreads();
    if (tau < 64) {                  // tau = b + 16*cidx, cidx in 0..3
      float u_raw = gat[tau];
      float c_raw = gat[tau + 64];
      float u  = 1.f / (1.f + __expf(-u_raw));
      float cc = tanhf(c_raw);
      int   pp = 4 * j + (tau >> 4);
      float hp = hcur[b * DD + pp];
      float hn = hp + u * (cc - hp);
      hnext[b * DD + pp] = hn;
      out[(size_t)b * SS * DD + (size_t)t * DD + pp] = hn;
      if (t == SS - 1) out[(size_t)BB * SS * DD + b * DD + pp] = hn;
    }
    grid_barrier(cnt, flg, phase++);
  }
  (void)bias; (void)col;
}

extern "C" void kernel_launch(void* const* d_in, const int* in_sizes, int n_in,
                              void* d_out, int out_size, void* d_ws, size_t ws_size,
                              hipStream_t stream) {
  (void)in_sizes; (void)n_in; (void)out_size;
  const float* x    = (const float*)d_in[0];
  const float* h0   = (const float*)d_in[1];
  const float* W_in = (const float*)d_in[2];
  const float* b_in = (const float*)d_in[3];
  const float* W_st = (const float*)d_in[4];
  float* out = (float*)d_out;
  float* wsf = (float*)d_ws;

  size_t need = 256 + (size_t)2 * BB * DD * 4 + (size_t)EE * WSTRIDE * 4;
  int use_wt = (ws_size >= need) ? 1 : 0;

  hipMemsetAsync(d_ws, 0, 256, stream);  // zero barrier state (ws is poisoned 0xAA)
  hipLaunchKernelGGL(mingru_persistent, dim3(NB), dim3(NT), 0, stream,
                     x, h0, W_in, b_in, W_st, out, wsf, use_wt);
}

// Round 2
// 40199.216 us; speedup vs baseline: 3.6031x; 3.6031x over previous
//
#include <hip/hip_runtime.h>
#include <cstdint>
#include <cstddef>

// MinGRU persistent MFMA scan. B=16, S=2048, D=1024, E=2D=2048.
// 128 blocks x 512 threads (1 block/CU, 8 waves). Block j owns h-cols [8j,8j+8)
// i.e. gate cols {8j..8j+8} (update) and {1024+8j..} (candidate) = N=16 MFMA tile.
// W (combined [2048k x 16n] slice) resident in LDS as bf16 hi/lo (split precision).
// A operand = [x_t || h] split to bf16 hi/mid/lo in global ws, read as fragments.
// 5 MFMA products: ah*bh + ah*bl + am*bh + am*bl + al*bh  (~fp32-class error).

#define BB 16
#define SS 2048
#define DD 1024
#define EE 2048
#define NBLK 128
#define NTHR 512
#define WSTR 2056   // LDS row stride (ushorts) per col: 4112 B -> bank shift 4, 2-way max

typedef __attribute__((ext_vector_type(8))) short short8b;
typedef __attribute__((ext_vector_type(4))) float float4v;

__device__ __forceinline__ unsigned short f2bf(float f) {
  unsigned u = __float_as_uint(f);
  return (unsigned short)((u + 0x7FFFu + ((u >> 16) & 1u)) >> 16);
}
__device__ __forceinline__ float bf2f(unsigned short s) {
  return __uint_as_float(((unsigned)s) << 16);
}

// Tree grid-barrier: 8 group counters (16 blocks each) -> root -> flag. Monotonic.
__device__ __forceinline__ void gbar(int* bar, int phase) {
  __syncthreads();
  if (threadIdx.x == 0) {
    __threadfence();
    int g = blockIdx.x & 7;
    int old = __hip_atomic_fetch_add(&bar[g * 64], 1, __ATOMIC_ACQ_REL, __HIP_MEMORY_SCOPE_AGENT);
    if ((old & 15) == 15) {
      int r = __hip_atomic_fetch_add(&bar[512], 1, __ATOMIC_ACQ_REL, __HIP_MEMORY_SCOPE_AGENT);
      if ((r & 7) == 7)
        __hip_atomic_store(&bar[576], phase, __ATOMIC_RELEASE, __HIP_MEMORY_SCOPE_AGENT);
    }
    while (__hip_atomic_load(&bar[576], __ATOMIC_ACQUIRE, __HIP_MEMORY_SCOPE_AGENT) < phase)
      __builtin_amdgcn_s_sleep(1);
    __threadfence();
  }
  __syncthreads();
}

__global__ __launch_bounds__(NTHR, 1) void mingru_mfma(
    const float* __restrict__ x, const float* __restrict__ h0,
    const float* __restrict__ W_in, const float* __restrict__ b_in,
    const float* __restrict__ W_state, float* __restrict__ out,
    unsigned char* __restrict__ ws)
{
  extern __shared__ unsigned char smem[];
  unsigned short* WTh = (unsigned short*)smem;                 // [16][WSTR]
  unsigned short* WTl = WTh + 16 * WSTR;                       // [16][WSTR]
  float* Cp    = (float*)(WTl + 16 * WSTR);                    // [8][64][4]
  float* gates = Cp + 8 * 64 * 4;                              // [16][16]
  float* bias  = gates + 256;                                  // [16]

  int* bar = (int*)ws;
  unsigned short* xs_hi  = (unsigned short*)(ws + 4096);       // [2][16][1024]
  unsigned short* xs_mid = xs_hi  + 2 * BB * DD;
  unsigned short* xs_lo  = xs_mid + 2 * BB * DD;
  unsigned short* hb_hi  = xs_lo  + 2 * BB * DD;               // [2][16][1024]
  unsigned short* hb_mid = hb_hi  + 2 * BB * DD;
  unsigned short* hb_lo  = hb_mid + 2 * BB * DD;

  const int tid = threadIdx.x, j = blockIdx.x;
  const int wid = tid >> 6, l = tid & 63;
  const int mn = l & 15, q = l >> 4;

  // ---------------- phase 0 ----------------
  // W slice -> LDS, split hi/lo
  for (int i = tid; i < 16 * EE; i += NTHR) {
    int n = i & 15, k = i >> 4;
    int col = (n < 8) ? (8 * j + n) : (DD + 8 * j + n - 8);
    float w = (k < DD) ? W_in[(size_t)k * EE + col]
                       : W_state[(size_t)(k - DD) * EE + col];
    unsigned short w1 = f2bf(w);
    unsigned short w2 = f2bf(w - bf2f(w1));
    WTh[n * WSTR + k] = w1;
    WTl[n * WSTR + k] = w2;
  }
  if (tid < 16) bias[tid] = b_in[(tid < 8) ? (8 * j + tid) : (DD + 8 * j + tid - 8)];

  float hreg = 0.f;
  if (tid < 128) {                       // pointwise owners: b = tid&15, pi = tid>>4
    int b = tid & 15, pi = tid >> 4;
    hreg = h0[b * DD + 8 * j + pi];
    int hoff = b * DD + 8 * j + pi;      // slab 0
    unsigned short h1 = f2bf(hreg); float r = hreg - bf2f(h1);
    unsigned short h2 = f2bf(r);    float r2 = r - bf2f(h2);
    unsigned short h3 = f2bf(r2);
    hb_hi[hoff] = h1; hb_mid[hoff] = h2; hb_lo[hoff] = h3;
  } else if (tid < 256) {                // xsplit for t=0 -> slab 0
    int e = j * 128 + (tid - 128);
    int b = e >> 10, k = e & 1023;
    float v = x[(size_t)b * SS * DD + k];   // t=0
    int off = b * DD + k;
    unsigned short x1 = f2bf(v); float r = v - bf2f(x1);
    unsigned short x2 = f2bf(r);  float r2 = r - bf2f(x2);
    unsigned short x3 = f2bf(r2);
    xs_hi[off] = x1; xs_mid[off] = x2; xs_lo[off] = x3;
  }
  gbar(bar, 1);

  // per-wave constant offsets
  const int kip  = (wid & 3) * 256;            // k offset within the 1024-wide part
  const int aoff = mn * DD + kip + q * 8;      // element offset into xs/hb arrays
  const int boff = mn * WSTR + wid * 256 + q * 8;  // global k = wid*256 + ...

  // ---------------- scan ----------------
  for (int t = 0; t < SS; ++t) {
    const int slab = t & 1;
    const unsigned short* ah = ((wid < 4) ? xs_hi  : hb_hi)  + slab * BB * DD;
    const unsigned short* am = ((wid < 4) ? xs_mid : hb_mid) + slab * BB * DD;
    const unsigned short* al = ((wid < 4) ? xs_lo  : hb_lo)  + slab * BB * DD;

    float4v acc0 = {0.f, 0.f, 0.f, 0.f};
    float4v acc1 = {0.f, 0.f, 0.f, 0.f};
    #pragma unroll
    for (int c = 0; c < 8; c += 2) {
      short8b ah0 = *(const short8b*)(ah + aoff + 32 * c);
      short8b am0 = *(const short8b*)(am + aoff + 32 * c);
      short8b al0 = *(const short8b*)(al + aoff + 32 * c);
      short8b bh0 = *(const short8b*)(WTh + boff + 32 * c);
      short8b bl0 = *(const short8b*)(WTl + boff + 32 * c);
      short8b ah1 = *(const short8b*)(ah + aoff + 32 * (c + 1));
      short8b am1 = *(const short8b*)(am + aoff + 32 * (c + 1));
      short8b al1 = *(const short8b*)(al + aoff + 32 * (c + 1));
      short8b bh1 = *(const short8b*)(WTh + boff + 32 * (c + 1));
      short8b bl1 = *(const short8b*)(WTl + boff + 32 * (c + 1));
      acc0 = __builtin_amdgcn_mfma_f32_16x16x32_bf16(ah0, bh0, acc0, 0, 0, 0);
      acc1 = __builtin_amdgcn_mfma_f32_16x16x32_bf16(ah1, bh1, acc1, 0, 0, 0);
      acc0 = __builtin_amdgcn_mfma_f32_16x16x32_bf16(ah0, bl0, acc0, 0, 0, 0);
      acc1 = __builtin_amdgcn_mfma_f32_16x16x32_bf16(ah1, bl1, acc1, 0, 0, 0);
      acc0 = __builtin_amdgcn_mfma_f32_16x16x32_bf16(am0, bh0, acc0, 0, 0, 0);
      acc1 = __builtin_amdgcn_mfma_f32_16x16x32_bf16(am1, bh1, acc1, 0, 0, 0);
      acc0 = __builtin_amdgcn_mfma_f32_16x16x32_bf16(am0, bl0, acc0, 0, 0, 0);
      acc1 = __builtin_amdgcn_mfma_f32_16x16x32_bf16(am1, bl1, acc1, 0, 0, 0);
      acc0 = __builtin_amdgcn_mfma_f32_16x16x32_bf16(al0, bh0, acc0, 0, 0, 0);
      acc1 = __builtin_amdgcn_mfma_f32_16x16x32_bf16(al1, bh1, acc1, 0, 0, 0);
    }
    acc0.x += acc1.x; acc0.y += acc1.y; acc0.z += acc1.z; acc0.w += acc1.w;

    *(float4v*)(Cp + (wid * 64 + l) * 4) = acc0;
    __syncthreads();

    if (tid < 256) {                     // reduce 8 wave-partials -> gates
      int n = tid & 15, b = tid >> 4;
      int lane = ((b >> 2) << 4) | n, reg = b & 3;
      float s = bias[n];
      #pragma unroll
      for (int w = 0; w < 8; ++w) s += Cp[(w * 64 + lane) * 4 + reg];
      gates[b * 16 + n] = s;
    }
    __syncthreads();

    if (tid < 128) {                     // pointwise + h split + out
      int b = tid & 15, pi = tid >> 4;
      float ug = gates[b * 16 + pi];
      float cg = gates[b * 16 + pi + 8];
      float u  = 1.f / (1.f + __expf(-ug));
      float cv = tanhf(cg);
      hreg = hreg + u * (cv - hreg);
      out[(size_t)b * SS * DD + (size_t)t * DD + 8 * j + pi] = hreg;
      int hoff = ((t + 1) & 1) * BB * DD + b * DD + 8 * j + pi;
      unsigned short h1 = f2bf(hreg); float r = hreg - bf2f(h1);
      unsigned short h2 = f2bf(r);    float r2 = r - bf2f(h2);
      unsigned short h3 = f2bf(r2);
      hb_hi[hoff] = h1; hb_mid[hoff] = h2; hb_lo[hoff] = h3;
      if (t == SS - 1) out[(size_t)BB * SS * DD + b * DD + 8 * j + pi] = hreg;
    } else if (tid < 256 && t + 1 < SS) {   // cooperative x-split for t+1
      int e = j * 128 + (tid - 128);
      int b = e >> 10, k = e & 1023;
      float v = x[(size_t)b * SS * DD + (size_t)(t + 1) * DD + k];
      int off = ((t + 1) & 1) * BB * DD + b * DD + k;
      unsigned short x1 = f2bf(v); float r = v - bf2f(x1);
      unsigned short x2 = f2bf(r);  float r2 = r - bf2f(x2);
      unsigned short x3 = f2bf(r2);
      xs_hi[off] = x1; xs_mid[off] = x2; xs_lo[off] = x3;
    }
    gbar(bar, t + 2);
  }
}

extern "C" void kernel_launch(void* const* d_in, const int* in_sizes, int n_in,
                              void* d_out, int out_size, void* d_ws, size_t ws_size,
                              hipStream_t stream) {
  (void)in_sizes; (void)n_in; (void)out_size; (void)ws_size;
  const float* x    = (const float*)d_in[0];
  const float* h0   = (const float*)d_in[1];
  const float* W_in = (const float*)d_in[2];
  const float* b_in = (const float*)d_in[3];
  const float* W_st = (const float*)d_in[4];
  float* out = (float*)d_out;

  const int smem_bytes = (2 * 16 * WSTR) * 2 + (8 * 64 * 4 + 256 + 16) * 4; // 140,864
  static int attr_set = 0;
  if (!attr_set) {   // idempotent host-side attribute; value never changes
    hipFuncSetAttribute((const void*)mingru_mfma,
                        hipFuncAttributeMaxDynamicSharedMemorySize, smem_bytes);
    attr_set = 1;
  }

  hipMemsetAsync(d_ws, 0, 4096, stream);  // barrier state (ws is poisoned 0xAA)
  hipLaunchKernelGGL(mingru_mfma, dim3(NBLK), dim3(NTHR), smem_bytes, stream,
                     x, h0, W_in, b_in, W_st, out, (unsigned char*)d_ws);
}

// Round 3
// 22455.081 us; speedup vs baseline: 6.4502x; 1.7902x over previous
//
#include <hip/hip_runtime.h>
#include <cstdint>
#include <cstddef>

// MinGRU persistent MFMA scan, round 3: fence-free cross-block communication.
// 128 blocks x 512 threads. Block j owns h-cols [8j,8j+8) -> gate cols
// {8j..}, {1024+8j..} (N=16 MFMA tile). W slice in LDS (bf16 hi/lo).
// A = [x_t || h]: x from precomputed bf16 hi/mid/lo arrays (plain loads),
// h exchanged via RELAXED agent-scope atomics (no wbl2/buffer_inv ever).

#define BB 16
#define SS 2048
#define DD 1024
#define EE 2048
#define NBLK 128
#define NTHR 512
#define WSTR 2056

typedef __attribute__((ext_vector_type(8))) short short8b;
typedef __attribute__((ext_vector_type(4))) float float4v;
typedef unsigned long long u64;
typedef unsigned short u16;

__device__ __forceinline__ u16 f2bf(float f) {
  unsigned u = __float_as_uint(f);
  return (u16)((u + 0x7FFFu + ((u >> 16) & 1u)) >> 16);
}
__device__ __forceinline__ float bf2f(u16 s) { return __uint_as_float(((unsigned)s) << 16); }
__device__ __forceinline__ u64 ald(const u64* p) {
  return __hip_atomic_load(p, __ATOMIC_RELAXED, __HIP_MEMORY_SCOPE_AGENT);
}

// Grid barrier: tree of RELAXED atomics. Correctness: __syncthreads drains each
// wave's write-through (sc1) stores (vmcnt(0)) => globally visible before the
// leader's arrival RMW; readers' loads are sc1-coherent so no inv needed.
__device__ __forceinline__ void gbar(int* bar, int phase) {
  __syncthreads();
  if (threadIdx.x == 0) {
    int g = blockIdx.x & 7;
    int old = __hip_atomic_fetch_add(&bar[g * 64], 1, __ATOMIC_RELAXED, __HIP_MEMORY_SCOPE_AGENT);
    if ((old & 15) == 15) {
      int r = __hip_atomic_fetch_add(&bar[512], 1, __ATOMIC_RELAXED, __HIP_MEMORY_SCOPE_AGENT);
      if ((r & 7) == 7)
        __hip_atomic_store(&bar[576], phase, __ATOMIC_RELAXED, __HIP_MEMORY_SCOPE_AGENT);
    }
    while (__hip_atomic_load(&bar[576], __ATOMIC_RELAXED, __HIP_MEMORY_SCOPE_AGENT) < phase)
      __builtin_amdgcn_s_sleep(1);
  }
  __syncthreads();
}

// Publish 128 owners' new h (waves 0,1; owner tid = b + 16*pi) as packed
// 3-split bf16, 4 cols per u64, via relaxed agent atomic stores.
__device__ __forceinline__ void publish_h(u64* hsl, int np, int j, int tid, float hn) {
  int src = (tid & 15);
  float g1 = __shfl(hn, src + 16, 64);
  float g2 = __shfl(hn, src + 32, 64);
  float g3 = __shfl(hn, src + 48, 64);
  if ((tid & 63) < 16) {
    int b = tid & 15, cg = tid >> 6;   // wave0 -> cols 8j+0..3, wave1 -> 8j+4..7
    float vals[4] = {hn, g1, g2, g3};
    u64 p0 = 0, p1 = 0, p2 = 0;
    #pragma unroll
    for (int i = 0; i < 4; ++i) {
      float f = vals[i];
      u16 a = f2bf(f); float r  = f - bf2f(a);
      u16 m = f2bf(r); float r2 = r - bf2f(m);
      u16 c = f2bf(r2);
      p0 |= (u64)a << (16 * i); p1 |= (u64)m << (16 * i); p2 |= (u64)c << (16 * i);
    }
    size_t base = (size_t)b * 256 + 2 * j + cg;
    __hip_atomic_store(&hsl[(size_t)(0 * 2 + np) * 4096 + base], p0, __ATOMIC_RELAXED, __HIP_MEMORY_SCOPE_AGENT);
    __hip_atomic_store(&hsl[(size_t)(1 * 2 + np) * 4096 + base], p1, __ATOMIC_RELAXED, __HIP_MEMORY_SCOPE_AGENT);
    __hip_atomic_store(&hsl[(size_t)(2 * 2 + np) * 4096 + base], p2, __ATOMIC_RELAXED, __HIP_MEMORY_SCOPE_AGENT);
  }
}

struct Frag { short8b h, m, l; };

__global__ __launch_bounds__(256) void xsplit_k(const float* __restrict__ x,
    u16* __restrict__ xh, u16* __restrict__ xm, u16* __restrict__ xl) {
  size_t i = ((size_t)blockIdx.x * 256 + threadIdx.x) * 4;
  float4v v = *(const float4v*)(x + i);
  u64 ph = 0, pm = 0, pl = 0;
  #pragma unroll
  for (int k = 0; k < 4; ++k) {
    float f = v[k];
    u16 a = f2bf(f); float r  = f - bf2f(a);
    u16 b = f2bf(r); float r2 = r - bf2f(b);
    u16 c = f2bf(r2);
    ph |= (u64)a << (16 * k); pm |= (u64)b << (16 * k); pl |= (u64)c << (16 * k);
  }
  *(u64*)(xh + i) = ph; *(u64*)(xm + i) = pm; *(u64*)(xl + i) = pl;
}

__global__ __launch_bounds__(NTHR, 1) void mingru_scan(
    const float* __restrict__ x, const float* __restrict__ h0,
    const float* __restrict__ W_in, const float* __restrict__ b_in,
    const float* __restrict__ W_state, float* __restrict__ out,
    unsigned char* __restrict__ ws, int use_xpre)
{
  extern __shared__ unsigned char smem[];
  u16* WTh = (u16*)smem;                       // [16][WSTR]
  u16* WTl = WTh + 16 * WSTR;                  // [16][WSTR]
  float* Cp    = (float*)(WTl + 16 * WSTR);    // [8][64][4]
  float* gates = Cp + 8 * 64 * 4;              // [16][16]
  float* bias  = gates + 256;                  // [16]

  int* bar = (int*)ws;
  u64* hsl = (u64*)(ws + 4096);                // [3 split][2 slab][16][256] u64
  const u16* xph = (const u16*)(ws + 262144);  // [16][2048][1024] each
  const u16* xpm = xph + (size_t)BB * SS * DD;
  const u16* xpl = xpm + (size_t)BB * SS * DD;

  const int tid = threadIdx.x, j = blockIdx.x;
  const int wid = tid >> 6, l = tid & 63;
  const int mn = l & 15, q = l >> 4;

  // ---- phase 0: W slice -> LDS split; bias; h0 publish ----
  for (int i = tid; i < 16 * EE; i += NTHR) {
    int n = i & 15, k = i >> 4;
    int col = (n < 8) ? (8 * j + n) : (DD + 8 * j + n - 8);
    float w = (k < DD) ? W_in[(size_t)k * EE + col]
                       : W_state[(size_t)(k - DD) * EE + col];
    u16 w1 = f2bf(w);
    u16 w2 = f2bf(w - bf2f(w1));
    WTh[n * WSTR + k] = w1;
    WTl[n * WSTR + k] = w2;
  }
  if (tid < 16) bias[tid] = b_in[(tid < 8) ? (8 * j + tid) : (DD + 8 * j + tid - 8)];

  float hreg = 0.f;
  if (tid < 128) {
    int b = tid & 15, pi = tid >> 4;
    hreg = h0[b * DD + 8 * j + pi];
    publish_h(hsl, 0, j, tid, hreg);
  }
  gbar(bar, 1);

  const int isH  = (wid >= 4);
  const int koff = wid * 256 + q * 8;                       // global k of chunk 0
  const int boff = mn * WSTR + koff;                        // B (LDS) offset
  const int hxb  = mn * 256 + (wid - 4) * 64 + 2 * q;       // h u64 index, chunk 0
  const size_t xrow = (size_t)mn * SS * DD;

  for (int t = 0; t < SS; ++t) {
    const int slab = t & 1;

    // ---- fetch all A fragments for this step (pipelined) ----
    Frag F[8];
    if (isH) {
      const u64* p0 = hsl + (size_t)(0 * 2 + slab) * 4096;
      const u64* p1 = hsl + (size_t)(1 * 2 + slab) * 4096;
      const u64* p2 = hsl + (size_t)(2 * 2 + slab) * 4096;
      #pragma unroll
      for (int c = 0; c < 8; ++c) {
        int ix = hxb + 8 * c;
        union { u64 u[2]; short8b v; } a0, a1, a2;
        a0.u[0] = ald(p0 + ix); a0.u[1] = ald(p0 + ix + 1);
        a1.u[0] = ald(p1 + ix); a1.u[1] = ald(p1 + ix + 1);
        a2.u[0] = ald(p2 + ix); a2.u[1] = ald(p2 + ix + 1);
        F[c].h = a0.v; F[c].m = a1.v; F[c].l = a2.v;
      }
    } else if (use_xpre) {
      size_t o = xrow + (size_t)t * DD + koff;
      #pragma unroll
      for (int c = 0; c < 8; ++c) {
        F[c].h = *(const short8b*)(xph + o + 32 * c);
        F[c].m = *(const short8b*)(xpm + o + 32 * c);
        F[c].l = *(const short8b*)(xpl + o + 32 * c);
      }
    } else {
      const float* xr = x + xrow + (size_t)t * DD + koff;
      #pragma unroll
      for (int c = 0; c < 8; ++c) {
        float vals[8];
        *(float4v*)vals       = *(const float4v*)(xr + 32 * c);
        *(float4v*)(vals + 4) = *(const float4v*)(xr + 32 * c + 4);
        union { u16 s[8]; short8b v; } H, M, L;
        #pragma unroll
        for (int i = 0; i < 8; ++i) {
          float f = vals[i];
          u16 a = f2bf(f); float r  = f - bf2f(a);
          u16 m = f2bf(r); float r2 = r - bf2f(m);
          u16 cc = f2bf(r2);
          H.s[i] = a; M.s[i] = m; L.s[i] = cc;
        }
        F[c].h = H.v; F[c].m = M.v; F[c].l = L.v;
      }
    }

    // ---- MFMA: 5-product split, two accumulator chains ----
    float4v acc0 = {0.f, 0.f, 0.f, 0.f};
    float4v acc1 = {0.f, 0.f, 0.f, 0.f};
    #pragma unroll
    for (int c = 0; c < 8; c += 2) {
      short8b bh0 = *(const short8b*)(WTh + boff + 32 * c);
      short8b bl0 = *(const short8b*)(WTl + boff + 32 * c);
      short8b bh1 = *(const short8b*)(WTh + boff + 32 * (c + 1));
      short8b bl1 = *(const short8b*)(WTl + boff + 32 * (c + 1));
      acc0 = __builtin_amdgcn_mfma_f32_16x16x32_bf16(F[c].h,     bh0, acc0, 0, 0, 0);
      acc1 = __builtin_amdgcn_mfma_f32_16x16x32_bf16(F[c + 1].h, bh1, acc1, 0, 0, 0);
      acc0 = __builtin_amdgcn_mfma_f32_16x16x32_bf16(F[c].h,     bl0, acc0, 0, 0, 0);
      acc1 = __builtin_amdgcn_mfma_f32_16x16x32_bf16(F[c + 1].h, bl1, acc1, 0, 0, 0);
      acc0 = __builtin_amdgcn_mfma_f32_16x16x32_bf16(F[c].m,     bh0, acc0, 0, 0, 0);
      acc1 = __builtin_amdgcn_mfma_f32_16x16x32_bf16(F[c + 1].m, bh1, acc1, 0, 0, 0);
      acc0 = __builtin_amdgcn_mfma_f32_16x16x32_bf16(F[c].m,     bl0, acc0, 0, 0, 0);
      acc1 = __builtin_amdgcn_mfma_f32_16x16x32_bf16(F[c + 1].m, bl1, acc1, 0, 0, 0);
      acc0 = __builtin_amdgcn_mfma_f32_16x16x32_bf16(F[c].l,     bh0, acc0, 0, 0, 0);
      acc1 = __builtin_amdgcn_mfma_f32_16x16x32_bf16(F[c + 1].l, bh1, acc1, 0, 0, 0);
    }
    acc0.x += acc1.x; acc0.y += acc1.y; acc0.z += acc1.z; acc0.w += acc1.w;

    *(float4v*)(Cp + (wid * 64 + l) * 4) = acc0;
    __syncthreads();

    if (tid < 256) {                 // reduce 8 wave-partials -> gates
      int n = tid & 15, b = tid >> 4;
      int lane = ((b >> 2) << 4) | n, reg = b & 3;
      float s = bias[n];
      #pragma unroll
      for (int w = 0; w < 8; ++w) s += Cp[(w * 64 + lane) * 4 + reg];
      gates[b * 16 + n] = s;
    }
    __syncthreads();

    if (tid < 128) {                 // pointwise + publish + out
      int b = tid & 15, pi = tid >> 4;
      float ug = gates[b * 16 + pi];
      float cg = gates[b * 16 + pi + 8];
      float u  = 1.f / (1.f + __expf(-ug));
      float cv = tanhf(cg);
      hreg = hreg + u * (cv - hreg);
      __builtin_nontemporal_store(hreg,
          out + (size_t)b * SS * DD + (size_t)t * DD + 8 * j + pi);
      publish_h(hsl, (t + 1) & 1, j, tid, hreg);
      if (t == SS - 1) out[(size_t)BB * SS * DD + b * DD + 8 * j + pi] = hreg;
    }
    gbar(bar, t + 2);
  }
}

extern "C" void kernel_launch(void* const* d_in, const int* in_sizes, int n_in,
                              void* d_out, int out_size, void* d_ws, size_t ws_size,
                              hipStream_t stream) {
  (void)in_sizes; (void)n_in; (void)out_size;
  const float* x    = (const float*)d_in[0];
  const float* h0   = (const float*)d_in[1];
  const float* W_in = (const float*)d_in[2];
  const float* b_in = (const float*)d_in[3];
  const float* W_st = (const float*)d_in[4];
  float* out = (float*)d_out;

  size_t need = 262144 + 3 * (size_t)BB * SS * DD * 2;   // ~192.3 MB
  int use_xpre = (ws_size >= need) ? 1 : 0;

  const int smem_bytes = (2 * 16 * WSTR) * 2 + (8 * 64 * 4 + 256 + 16) * 4; // 140,864
  static int attr_set = 0;
  if (!attr_set) {
    hipFuncSetAttribute((const void*)mingru_scan,
                        hipFuncAttributeMaxDynamicSharedMemorySize, smem_bytes);
    attr_set = 1;
  }

  hipMemsetAsync(d_ws, 0, 4096, stream);   // barrier state
  if (use_xpre) {
    u16* xh = (u16*)((unsigned char*)d_ws + 262144);
    u16* xm = xh + (size_t)BB * SS * DD;
    u16* xl = xm + (size_t)BB * SS * DD;
    hipLaunchKernelGGL(xsplit_k, dim3(32768), dim3(256), 0, stream, x, xh, xm, xl);
  }
  hipLaunchKernelGGL(mingru_scan, dim3(NBLK), dim3(NTHR), smem_bytes, stream,
                     x, h0, W_in, b_in, W_st, out, (unsigned char*)d_ws, use_xpre);
}